// Round 5
// baseline (1234.652 us; speedup 1.0000x reference)
//
#include <hip/hip_runtime.h>
#include <hip/hip_cooperative_groups.h>
#include <math.h>

namespace cg = cooperative_groups;

#define D 128
#define NB 8
#define NN1 128
#define NN2 512
#define ROWS1 (NB * NN1)          // 1024
#define ROWS2 (NB * NN2)          // 4096
#define ROWS (ROWS1 + ROWS2)      // 5120
#define CAP1 96
#define CAP2 160
#define CSR_ELEMS ((size_t)ROWS1 * CAP1 + (size_t)ROWS2 * CAP2)

struct KParams {
    const float *h1, *adj1, *h2, *adj2, *A_int, *pos1, *pos2, *rotor, *vr1, *vr2,
                *duff, *nm1, *nm2, *nodeW, *gatW, *gatb, *gatA, *gateW, *gateb,
                *vA_W1, *vA_b1, *vA_W2, *vA_b2, *vB_W1, *vB_b1, *vB_W2, *vB_b2,
                *hbond, *hydro, *vdwc, *rotc;
    float *g, *hbuf, *hAbuf, *svals, *partials, *out;
    float2 *rowstat;
    unsigned short *csr;
    int *nnz;
};

__device__ __forceinline__ void resolve_row(int row, int& base_row, size_t& cbase,
                                            int& N) {
    if (row < ROWS1) {
        base_row = row & ~127;
        cbase = (size_t)row * CAP1;
        N = NN1;
    } else {
        int r = row - ROWS1;
        base_row = ROWS1 + (r & ~511);
        cbase = (size_t)ROWS1 * CAP1 + (size_t)r * CAP2;
        N = NN2;
    }
}

__global__ __launch_bounds__(256, 4) void k_mega(KParams pp) {
    cg::grid_group grid = cg::this_grid();
    const int t = threadIdx.x;
    const int bid = blockIdx.x;
    const int G = gridDim.x;

    __shared__ union SMem {
        struct { float xr[2][56]; } p0;
        struct { float xs[16][D]; float hs[16][D]; } ph;
        struct { float sv[2][CAP2]; } pb;
        struct { float avals[2][CAP2]; int aidx[2][CAP2]; float red[256]; } pc;
        struct { float A1a[32][20], A1b[32][20], A2a[32][20], A2b[32][20];
                 float w2As[D], w2Bs[D], zAs[32][33], zBs[32][33]; } pe;
        struct { float r[4][128]; } pf;
    } sm;

    // ---------------- phase 0: embed + CSR (2 rows / block) ----------------
    for (int r0 = bid * 2; r0 < ROWS; r0 += 2 * G) {
        __syncthreads();
        int half = t >> 7, t2 = t & 127;
        int row = r0 + half;
        const float* src = (row < ROWS1) ? pp.h1 + (size_t)row * 54
                                         : pp.h2 + (size_t)(row - ROWS1) * 54;
        if (t2 < 54) sm.p0.xr[half][t2] = src[t2];
        __syncthreads();
        float a0 = 0.f, a1 = 0.f;
#pragma unroll
        for (int k = 0; k < 54; k += 2) {
            a0 += sm.p0.xr[half][k] * pp.nodeW[k * D + t2];
            if (k + 1 < 54) a1 += sm.p0.xr[half][k + 1] * pp.nodeW[(k + 1) * D + t2];
        }
        pp.g[(size_t)row * D + t2] = a0 + a1;
        if (t2 < 64) {   // full wave (waves 0 and 2)
            int base_row, N; size_t cbase;
            resolve_row(row, base_row, cbase, N);
            int cap = (row < ROWS1) ? CAP1 : CAP2;
            const float* arow = (row < ROWS1)
                                    ? pp.adj1 + (size_t)row * NN1
                                    : pp.adj2 + (size_t)(row - ROWS1) * NN2;
            int cnt = 0;
            for (int c0 = 0; c0 < N; c0 += 64) {
                float v = arow[c0 + t2];
                unsigned long long m = __ballot(v > 0.f);
                int rank = __popcll(m & ((1ull << t2) - 1ull));
                if (v > 0.f && cnt + rank < cap)
                    pp.csr[cbase + cnt + rank] = (unsigned short)(c0 + t2);
                cnt += __popcll(m);
            }
            if (t2 == 0) pp.nnz[row] = cnt < cap ? cnt : cap;
        }
    }
    grid.sync();

    // ---------------- 3 GAT layers ----------------
    for (int l = 0; l < 3; ++l) {
        const float* W  = pp.gatW  + (size_t)l * D * D;
        const float* bb = pp.gatb  + (size_t)l * D;
        const float* A  = pp.gatA  + (size_t)l * D * D;
        const float* gW = pp.gateW + (size_t)l * 2 * D;
        const float  gb0 = pp.gateb[l];

        // ---- phase A: h = g@W + b ; hA = h@A (16 rows / block) ----
        for (int grp = bid; grp < ROWS / 16; grp += G) {
            __syncthreads();
            int row0 = grp * 16;
            int d = t & 127, rh = t >> 7;
            {
                int r = t >> 4, c = (t & 15) * 8;
                *(float4*)&sm.ph.xs[r][c] = *(const float4*)&pp.g[((size_t)row0 + r) * D + c];
                *(float4*)&sm.ph.xs[r][c + 4] = *(const float4*)&pp.g[((size_t)row0 + r) * D + c + 4];
            }
            __syncthreads();
            float bv = bb[d];
            float acc[8];
#pragma unroll
            for (int u = 0; u < 8; ++u) acc[u] = bv;
            for (int k0 = 0; k0 < D; k0 += 4) {
                float w0 = W[(k0 + 0) * D + d];
                float w1 = W[(k0 + 1) * D + d];
                float w2 = W[(k0 + 2) * D + d];
                float w3 = W[(k0 + 3) * D + d];
#pragma unroll
                for (int u = 0; u < 8; ++u) {
                    float4 xv = *(const float4*)&sm.ph.xs[rh * 8 + u][k0];
                    acc[u] += xv.x * w0 + xv.y * w1 + xv.z * w2 + xv.w * w3;
                }
            }
#pragma unroll
            for (int u = 0; u < 8; ++u) {
                int r = rh * 8 + u;
                pp.hbuf[((size_t)row0 + r) * D + d] = acc[u];
                sm.ph.hs[r][d] = acc[u];
            }
            __syncthreads();
            float acc2[8];
#pragma unroll
            for (int u = 0; u < 8; ++u) acc2[u] = 0.f;
            for (int k0 = 0; k0 < D; k0 += 4) {
                float w0 = A[(k0 + 0) * D + d];
                float w1 = A[(k0 + 1) * D + d];
                float w2 = A[(k0 + 2) * D + d];
                float w3 = A[(k0 + 3) * D + d];
#pragma unroll
                for (int u = 0; u < 8; ++u) {
                    float4 xv = *(const float4*)&sm.ph.hs[rh * 8 + u][k0];
                    acc2[u] += xv.x * w0 + xv.y * w1 + xv.z * w2 + xv.w * w3;
                }
            }
#pragma unroll
            for (int u = 0; u < 8; ++u)
                pp.hAbuf[((size_t)row0 + rh * 8 + u) * D + d] = acc2[u];
        }
        grid.sync();

        // ---- phase B: sparse S + softmax stats (R3 logic, 2 rows / block) ----
        for (int r0 = bid * 2; r0 < ROWS; r0 += 2 * G) {
            __syncthreads();
            int half = t >> 7, t2 = t & 127;
            int row = r0 + half;
            int base_row, N; size_t cbase;
            resolve_row(row, base_row, cbase, N);
            int n = pp.nnz[row];
            int grp8 = t2 >> 4, u = t2 & 15;
            const float* hrow = pp.hbuf + (size_t)row * D + u * 8;
            const float* hArow = pp.hAbuf + (size_t)row * D + u * 8;
            float4 hi0 = *(const float4*)&hrow[0], hi1 = *(const float4*)&hrow[4];
            float4 ai0 = *(const float4*)&hArow[0], ai1 = *(const float4*)&hArow[4];
            float* sv = sm.pb.sv[half];
            for (int s0 = 0; s0 < n; s0 += 8) {
                int s = s0 + grp8;
                float pv = 0.f;
                if (s < n) {
                    int jrow = base_row + pp.csr[cbase + s];
                    const float* hj = pp.hbuf + (size_t)jrow * D + u * 8;
                    const float* aj = pp.hAbuf + (size_t)jrow * D + u * 8;
                    float4 hj0 = *(const float4*)&hj[0], hj1 = *(const float4*)&hj[4];
                    float4 aj0 = *(const float4*)&aj[0], aj1 = *(const float4*)&aj[4];
                    pv = hi0.x * aj0.x + hi0.y * aj0.y + hi0.z * aj0.z + hi0.w * aj0.w +
                         hi1.x * aj1.x + hi1.y * aj1.y + hi1.z * aj1.z + hi1.w * aj1.w +
                         ai0.x * hj0.x + ai0.y * hj0.y + ai0.z * hj0.z + ai0.w * hj0.w +
                         ai1.x * hj1.x + ai1.y * hj1.y + ai1.z * hj1.z + ai1.w * hj1.w;
                }
                pv += __shfl_xor(pv, 8);
                pv += __shfl_xor(pv, 4);
                pv += __shfl_xor(pv, 2);
                pv += __shfl_xor(pv, 1);
                if (s < n && u == 0) sv[s] = pv;
            }
            __syncthreads();
            if (t2 < 64) {   // full wave per half
                float m = -3.4e38f;
                for (int s = t2; s < n; s += 64) m = fmaxf(m, sv[s]);
#pragma unroll
                for (int o = 32; o > 0; o >>= 1) m = fmaxf(m, __shfl_xor(m, o));
                float sum = 0.f;
                for (int s = t2; s < n; s += 64) sum += expf(sv[s] - m);
#pragma unroll
                for (int o = 32; o > 0; o >>= 1) sum += __shfl_xor(sum, o);
                if (t2 == 0) pp.rowstat[row] = make_float2(m, 1.f / sum);
            }
            for (int s = t2; s < n; s += 128) pp.svals[cbase + s] = sv[s];
        }
        grid.sync();

        // ---- phase C: h_prime via symmetry + gate (R3 logic, 2 rows / block) ----
        for (int r0 = bid * 2; r0 < ROWS; r0 += 2 * G) {
            __syncthreads();
            int half = t >> 7, d = t & 127;
            int row = r0 + half;
            int base_row, N; size_t cbase;
            resolve_row(row, base_row, cbase, N);
            int n = pp.nnz[row];
            float* avals = sm.pc.avals[half];
            int* aidx = sm.pc.aidx[half];
            for (int s = d; s < n; s += 128) {
                int jrow = base_row + pp.csr[cbase + s];
                float2 st = pp.rowstat[jrow];
                avals[s] = expf(pp.svals[cbase + s] - st.x) * st.y;
                aidx[s] = jrow;
            }
            __syncthreads();
            float a0 = 0.f, a1 = 0.f, a2 = 0.f, a3 = 0.f;
            int s = 0;
            for (; s + 4 <= n; s += 4) {
                a0 += avals[s + 0] * pp.hbuf[(size_t)aidx[s + 0] * D + d];
                a1 += avals[s + 1] * pp.hbuf[(size_t)aidx[s + 1] * D + d];
                a2 += avals[s + 2] * pp.hbuf[(size_t)aidx[s + 2] * D + d];
                a3 += avals[s + 3] * pp.hbuf[(size_t)aidx[s + 3] * D + d];
            }
            for (; s < n; ++s) a0 += avals[s] * pp.hbuf[(size_t)aidx[s] * D + d];
            float hv = fmaxf(a0 + a1 + a2 + a3, 0.f);
            float xv = pp.g[(size_t)row * D + d];
            sm.pc.red[t] = xv * gW[d] + hv * gW[D + d];
            __syncthreads();
            for (int o = 64; o > 0; o >>= 1) {
                if ((t & 127) < o) sm.pc.red[t] += sm.pc.red[t + o];
                __syncthreads();
            }
            float c = 1.f / (1.f + expf(-(sm.pc.red[half * 128] + gb0)));
            pp.g[(size_t)row * D + d] = c * xv + (1.f - c) * hv;
        }
        grid.sync();
    }

    // ---- phase D: pair-MLP precompute (aA=hbuf, aB=hAbuf) ----
    for (int grp = bid; grp < ROWS / 16; grp += G) {
        __syncthreads();
        int row0 = grp * 16;
        int d = t & 127, rh = t >> 7;
        int g2 = (row0 >= ROWS1);
        const float* WAp = g2 ? pp.vA_W1 + D * D : pp.vA_W1;
        const float* WBp = g2 ? pp.vB_W1 + D * D : pp.vB_W1;
        {
            int r = t >> 4, c = (t & 15) * 8;
            *(float4*)&sm.ph.xs[r][c] = *(const float4*)&pp.g[((size_t)row0 + r) * D + c];
            *(float4*)&sm.ph.xs[r][c + 4] = *(const float4*)&pp.g[((size_t)row0 + r) * D + c + 4];
        }
        __syncthreads();
        float bvA = g2 ? 0.f : pp.vA_b1[d];
        float bvB = g2 ? 0.f : pp.vB_b1[d];
        float accA[8], accB[8];
#pragma unroll
        for (int u = 0; u < 8; ++u) { accA[u] = bvA; accB[u] = bvB; }
        for (int k0 = 0; k0 < D; k0 += 4) {
            float wa0 = WAp[(k0 + 0) * D + d], wa1 = WAp[(k0 + 1) * D + d];
            float wa2 = WAp[(k0 + 2) * D + d], wa3 = WAp[(k0 + 3) * D + d];
            float wb0 = WBp[(k0 + 0) * D + d], wb1 = WBp[(k0 + 1) * D + d];
            float wb2 = WBp[(k0 + 2) * D + d], wb3 = WBp[(k0 + 3) * D + d];
#pragma unroll
            for (int u = 0; u < 8; ++u) {
                float4 xv = *(const float4*)&sm.ph.xs[rh * 8 + u][k0];
                accA[u] += xv.x * wa0 + xv.y * wa1 + xv.z * wa2 + xv.w * wa3;
                accB[u] += xv.x * wb0 + xv.y * wb1 + xv.z * wb2 + xv.w * wb3;
            }
        }
#pragma unroll
        for (int u = 0; u < 8; ++u) {
            int r = rh * 8 + u;
            pp.hbuf[((size_t)row0 + r) * D + d] = accA[u];
            pp.hAbuf[((size_t)row0 + r) * D + d] = accB[u];
        }
    }
    grid.sync();

    // ---- phase E: pair z-GEMM + energies (512 tiles) ----
    for (int tile = bid; tile < 512; tile += G) {
        int b = tile >> 6;
        int itile = (tile >> 4) & 3, jtile = tile & 15;
        int i0 = itile * 32, j0 = jtile * 32;
        int tx = t & 15, ty = t >> 4;
        if (t < 128) { sm.pe.w2As[t] = pp.vA_W2[t]; sm.pe.w2Bs[t] = pp.vB_W2[t]; }
        float zA[2][2] = {{0.f, 0.f}, {0.f, 0.f}};
        float zB[2][2] = {{0.f, 0.f}, {0.f, 0.f}};
        int half = t >> 7, idx = t & 127;
        int sr = idx >> 2, sc = (idx & 3) * 4;
        size_t grow = half ? (size_t)(ROWS1 + b * NN2 + j0 + sr)
                           : (size_t)(b * NN1 + i0 + sr);
        for (int hc = 0; hc < D; hc += 16) {
            __syncthreads();
            float4 va = *(const float4*)&pp.hbuf[grow * D + hc + sc];
            float4 vb = *(const float4*)&pp.hAbuf[grow * D + hc + sc];
            if (half) { *(float4*)&sm.pe.A2a[sr][sc] = va; *(float4*)&sm.pe.A2b[sr][sc] = vb; }
            else      { *(float4*)&sm.pe.A1a[sr][sc] = va; *(float4*)&sm.pe.A1b[sr][sc] = vb; }
            __syncthreads();
#pragma unroll
            for (int hh = 0; hh < 16; hh += 4) {
                float4 wA = *(const float4*)&sm.pe.w2As[hc + hh];
                float4 wB = *(const float4*)&sm.pe.w2Bs[hc + hh];
                float4 xA0 = *(const float4*)&sm.pe.A1a[ty][hh];
                float4 xA1 = *(const float4*)&sm.pe.A1a[ty + 16][hh];
                float4 xB0 = *(const float4*)&sm.pe.A1b[ty][hh];
                float4 xB1 = *(const float4*)&sm.pe.A1b[ty + 16][hh];
                float4 yA0 = *(const float4*)&sm.pe.A2a[tx][hh];
                float4 yA1 = *(const float4*)&sm.pe.A2a[tx + 16][hh];
                float4 yB0 = *(const float4*)&sm.pe.A2b[tx][hh];
                float4 yB1 = *(const float4*)&sm.pe.A2b[tx + 16][hh];
#define RD4(xx, yy, ww) (fmaxf(xx.x + yy.x, 0.f) * ww.x + fmaxf(xx.y + yy.y, 0.f) * ww.y + \
                         fmaxf(xx.z + yy.z, 0.f) * ww.z + fmaxf(xx.w + yy.w, 0.f) * ww.w)
                zA[0][0] += RD4(xA0, yA0, wA); zA[0][1] += RD4(xA0, yA1, wA);
                zA[1][0] += RD4(xA1, yA0, wA); zA[1][1] += RD4(xA1, yA1, wA);
                zB[0][0] += RD4(xB0, yB0, wB); zB[0][1] += RD4(xB0, yB1, wB);
                zB[1][0] += RD4(xB1, yB0, wB); zB[1][1] += RD4(xB1, yB1, wB);
#undef RD4
            }
        }
#pragma unroll
        for (int u = 0; u < 2; ++u)
#pragma unroll
            for (int v = 0; v < 2; ++v) {
                sm.pe.zAs[ty + 16 * u][tx + 16 * v] = zA[u][v];
                sm.pe.zBs[ty + 16 * u][tx + 16 * v] = zB[u][v];
            }
        __syncthreads();
        int j2 = t & 31, ig = t >> 5;
        int jg = j0 + j2;
        size_t j_off = (size_t)b * NN2 + jg;
        float p2x = pp.pos2[j_off * 3 + 0], p2y = pp.pos2[j_off * 3 + 1],
              p2z = pp.pos2[j_off * 3 + 2];
        float r2 = pp.vr2[j_off], m2 = pp.nm2[j_off];
        float zb2A = pp.vA_b2[0], zb2B = pp.vB_b2[0];
        float eV[4], e1[4], e2[4], eH[4];
#pragma unroll
        for (int ii = 0; ii < 4; ++ii) {
            int il = ig * 4 + ii;
            int iglob = i0 + il;
            size_t i_off = (size_t)b * NN1 + iglob;
            float zAv = sm.pe.zAs[il][j2] + zb2A;
            float zBv = sm.pe.zBs[il][j2] + zb2B;
            float dx = pp.pos1[i_off * 3 + 0] - p2x;
            float dy = pp.pos1[i_off * 3 + 1] - p2y;
            float dz = pp.pos1[i_off * 3 + 2] - p2z;
            float dm = sqrtf(dx * dx + dy * dy + dz * dz + 1e-10f);
            if (dm < 0.5f) dm = 1e10f;
            float A_w = 1.f / (1.f + expf(-zAv));
            float B_w = tanhf(zBv) * 0.2f;
            float dm0 = pp.vr1[i_off] + r2 + B_w;
            float dm0s = (dm0 < 1e-4f) ? 1.f : dm0;
            float rr = dm0s / dm;
            float rr2 = rr * rr;
            float rN = rr2 * rr2 * rr2;
            float evdw = fminf(rN * rN - 2.f * rN, 100.f);
            float mask = pp.nm1[i_off] * m2;
            float Aamp = A_w * (0.0356f - 0.0178f) + 0.0178f;
            eV[ii] = Aamp * evdw * mask;
            float dmd = dm - dm0;
            size_t abase = (((size_t)b * 8) * NN1 + iglob) * NN2 + jg;
            float Ai1 = pp.A_int[abase + (size_t)1 * NN1 * NN2];
            float Ai6 = pp.A_int[abase + (size_t)6 * NN1 * NN2];
            float Ai7 = pp.A_int[abase + (size_t)7 * NN1 * NN2];
            e1[ii] = fminf(fmaxf(dmd * Ai1 * (-1.f / 0.7f), 0.f), 1.f);
            e2[ii] = fminf(fmaxf(dmd * Ai7 * (-1.f / 0.7f), 0.f), 1.f);
            eH[ii] = fminf(fmaxf((1.5f - dmd) * Ai6, 0.f), 1.f);
        }
#pragma unroll
        for (int o = 16; o > 0; o >>= 1) {
#pragma unroll
            for (int ii = 0; ii < 4; ++ii) {
                eV[ii] += __shfl_xor(eV[ii], o);
                e1[ii] += __shfl_xor(e1[ii], o);
                e2[ii] += __shfl_xor(e2[ii], o);
                eH[ii] += __shfl_xor(eH[ii], o);
            }
        }
        if (j2 == 0) {
#pragma unroll
            for (int ii = 0; ii < 4; ++ii) {
                int iglob = i0 + ig * 4 + ii;
                float* po = pp.partials + (((size_t)b * NN1 + iglob) * 16 + jtile) * 4;
                po[0] = eV[ii]; po[1] = e1[ii]; po[2] = e2[ii]; po[3] = eH[ii];
            }
        }
        __syncthreads();
    }
    grid.sync();

    // ---- phase F: final reduction (blocks 0..7) ----
    if (bid < NB) {
        int b = bid;
        if (t < 128) {
            float v0 = 0.f, v1 = 0.f, v2 = 0.f, v3 = 0.f;
            const float* pr = pp.partials + ((size_t)b * NN1 + t) * 16 * 4;
#pragma unroll
            for (int jt = 0; jt < 16; ++jt) {
                v0 += pr[jt * 4 + 0]; v1 += pr[jt * 4 + 1];
                v2 += pr[jt * 4 + 2]; v3 += pr[jt * 4 + 3];
            }
            sm.pf.r[0][t] = v0; sm.pf.r[1][t] = v1;
            sm.pf.r[2][t] = v2; sm.pf.r[3][t] = v3;
        }
        __syncthreads();
        for (int s = 64; s > 0; s >>= 1) {
            if (t < s) {
                sm.pf.r[0][t] += sm.pf.r[0][t + s];
                sm.pf.r[1][t] += sm.pf.r[1][t + s];
                sm.pf.r[2][t] += sm.pf.r[2][t + s];
                sm.pf.r[3][t] += sm.pf.r[3][t + s];
            }
            __syncthreads();
        }
        if (t == 0) {
            float hb = -pp.hbond[0] * pp.hbond[0];
            float hy = -pp.hydro[0] * pp.hydro[0];
            float Et = pp.duff[b] * pp.vdwc[0] * pp.vdwc[0];
            float scl = 1.f / (1.f + pp.rotc[0] * pp.rotc[0] * pp.rotor[b]);
            pp.out[b * 5 + 0] = sm.pf.r[0][0] * scl;
            pp.out[b * 5 + 1] = sm.pf.r[1][0] * hb * scl;
            pp.out[b * 5 + 2] = sm.pf.r[2][0] * hb * scl;
            pp.out[b * 5 + 3] = sm.pf.r[3][0] * hy * scl;
            pp.out[b * 5 + 4] = Et * scl;
        }
    }
}

extern "C" void kernel_launch(void* const* d_in, const int* in_sizes, int n_in,
                              void* d_out, int out_size, void* d_ws, size_t ws_size,
                              hipStream_t stream) {
    KParams prm;
    prm.h1    = (const float*)d_in[0];
    prm.adj1  = (const float*)d_in[1];
    prm.h2    = (const float*)d_in[2];
    prm.adj2  = (const float*)d_in[3];
    prm.A_int = (const float*)d_in[4];
    prm.pos1  = (const float*)d_in[5];
    prm.pos2  = (const float*)d_in[6];
    prm.rotor = (const float*)d_in[7];
    prm.vr1   = (const float*)d_in[8];
    prm.vr2   = (const float*)d_in[9];
    prm.duff  = (const float*)d_in[10];
    prm.nm1   = (const float*)d_in[11];
    prm.nm2   = (const float*)d_in[12];
    prm.nodeW = (const float*)d_in[13];
    prm.gatW  = (const float*)d_in[14];
    prm.gatb  = (const float*)d_in[15];
    prm.gatA  = (const float*)d_in[16];
    prm.gateW = (const float*)d_in[17];
    prm.gateb = (const float*)d_in[18];
    prm.vA_W1 = (const float*)d_in[19];
    prm.vA_b1 = (const float*)d_in[20];
    prm.vA_W2 = (const float*)d_in[21];
    prm.vA_b2 = (const float*)d_in[22];
    prm.vB_W1 = (const float*)d_in[23];
    prm.vB_b1 = (const float*)d_in[24];
    prm.vB_W2 = (const float*)d_in[25];
    prm.vB_b2 = (const float*)d_in[26];
    prm.hbond = (const float*)d_in[27];
    prm.hydro = (const float*)d_in[28];
    prm.vdwc  = (const float*)d_in[29];
    prm.rotc  = (const float*)d_in[30];

    float* p = (float*)d_ws;
    prm.g     = p; p += (size_t)ROWS * D;
    prm.hbuf  = p; p += (size_t)ROWS * D;
    prm.hAbuf = p; p += (size_t)ROWS * D;
    prm.svals = p; p += CSR_ELEMS;
    prm.rowstat = (float2*)p; p += 2 * (size_t)ROWS;
    prm.partials = p; p += (size_t)NB * NN1 * 16 * 4;
    prm.csr = (unsigned short*)p;
    prm.nnz = (int*)(prm.csr + CSR_ELEMS);
    prm.out = (float*)d_out;

    int dev = 0;
    hipGetDevice(&dev);
    hipDeviceProp_t props;
    hipGetDeviceProperties(&props, dev);
    int maxB = 0;
    hipOccupancyMaxActiveBlocksPerMultiprocessor(&maxB,
        reinterpret_cast<const void*>(k_mega), 256, 0);
    if (maxB < 1) maxB = 1;
    long long Gl = (long long)maxB * props.multiProcessorCount;
    int G = (Gl > 1024) ? 1024 : (int)Gl;
    if (G < NB) G = NB;

    void* args[] = {(void*)&prm};
    hipLaunchCooperativeKernel(reinterpret_cast<const void*>(k_mega),
                               dim3(G), dim3(256), args, 0u, stream);
}

// Round 6
// 313.281 us; speedup vs baseline: 3.9410x; 3.9410x over previous
//
#include <hip/hip_runtime.h>
#include <math.h>

#define D 128
#define NB 8
#define NN1 128
#define NN2 512
#define ROWS1 (NB * NN1)          // 1024
#define ROWS2 (NB * NN2)          // 4096
#define ROWS (ROWS1 + ROWS2)      // 5120
#define CAP1 96
#define CAP2 160
#define CSR_ELEMS ((size_t)ROWS1 * CAP1 + (size_t)ROWS2 * CAP2)

__device__ __forceinline__ void resolve_row(int row, int& base_row, size_t& cbase,
                                            int& N) {
    if (row < ROWS1) {
        base_row = row & ~127;
        cbase = (size_t)row * CAP1;
        N = NN1;
    } else {
        int r = row - ROWS1;
        base_row = ROWS1 + (r & ~511);
        cbase = (size_t)ROWS1 * CAP1 + (size_t)r * CAP2;
        N = NN2;
    }
}

// ------- fused: node embed (128 thr) + CSR build (wave 0) + out zero -------
__global__ __launch_bounds__(128) void k_csrembed(
    const float* __restrict__ h1, const float* __restrict__ h2,
    const float* __restrict__ adj1, const float* __restrict__ adj2,
    const float* __restrict__ W, float* __restrict__ g,
    unsigned short* __restrict__ csr, int* __restrict__ nnz,
    float* __restrict__ out) {
    int row = blockIdx.x;
    int t = threadIdx.x;
    if (row == 0 && t < NB * 5) out[t] = 0.f;   // zero the atomic output
    const float* src = (row < ROWS1) ? h1 + (size_t)row * 54
                                     : h2 + (size_t)(row - ROWS1) * 54;
    __shared__ float xr[56];
    if (t < 54) xr[t] = src[t];
    __syncthreads();
    float a0 = 0.f, a1 = 0.f;
#pragma unroll
    for (int k = 0; k < 54; k += 2) {
        a0 += xr[k] * W[k * D + t];
        if (k + 1 < 54) a1 += xr[k + 1] * W[(k + 1) * D + t];
    }
    g[(size_t)row * D + t] = a0 + a1;

    if (t < 64) {
        int base_row, N;
        size_t cbase;
        resolve_row(row, base_row, cbase, N);
        int cap = (row < ROWS1) ? CAP1 : CAP2;
        const float* arow = (row < ROWS1)
                                ? adj1 + (size_t)row * NN1
                                : adj2 + (size_t)(row - ROWS1) * NN2;
        int cnt = 0;
        for (int c0 = 0; c0 < N; c0 += 64) {
            float v = arow[c0 + t];
            unsigned long long m = __ballot(v > 0.f);
            int rank = __popcll(m & ((1ull << t) - 1ull));
            if (v > 0.f && cnt + rank < cap)
                csr[cbase + cnt + rank] = (unsigned short)(c0 + t);
            cnt += __popcll(m);
        }
        if (t == 0) nnz[row] = cnt < cap ? cnt : cap;
    }
}

// ---------------- h = g@W + b ; hA = h@A  (16 rows / block) ----------------
__global__ __launch_bounds__(256) void k_h(const float* __restrict__ g,
                                           const float* __restrict__ W,
                                           const float* __restrict__ bias,
                                           const float* __restrict__ A,
                                           float* __restrict__ h, float* __restrict__ hA) {
    int row0 = blockIdx.x * 16;
    int t = threadIdx.x;
    int d = t & 127, rh = t >> 7;
    __shared__ float xs[16][D];
    __shared__ float hs[16][D];
    {
        int r = t >> 4, c = (t & 15) * 8;
        *(float4*)&xs[r][c] = *(const float4*)&g[((size_t)row0 + r) * D + c];
        *(float4*)&xs[r][c + 4] = *(const float4*)&g[((size_t)row0 + r) * D + c + 4];
    }
    __syncthreads();
    float bv = bias[d];
    float acc[8];
#pragma unroll
    for (int u = 0; u < 8; ++u) acc[u] = bv;
    for (int k0 = 0; k0 < D; k0 += 4) {
        float w0 = W[(k0 + 0) * D + d];
        float w1 = W[(k0 + 1) * D + d];
        float w2 = W[(k0 + 2) * D + d];
        float w3 = W[(k0 + 3) * D + d];
#pragma unroll
        for (int u = 0; u < 8; ++u) {
            float4 xv = *(const float4*)&xs[rh * 8 + u][k0];
            acc[u] += xv.x * w0 + xv.y * w1 + xv.z * w2 + xv.w * w3;
        }
    }
#pragma unroll
    for (int u = 0; u < 8; ++u) {
        int r = rh * 8 + u;
        h[((size_t)row0 + r) * D + d] = acc[u];
        hs[r][d] = acc[u];
    }
    __syncthreads();
    float acc2[8];
#pragma unroll
    for (int u = 0; u < 8; ++u) acc2[u] = 0.f;
    for (int k0 = 0; k0 < D; k0 += 4) {
        float w0 = A[(k0 + 0) * D + d];
        float w1 = A[(k0 + 1) * D + d];
        float w2 = A[(k0 + 2) * D + d];
        float w3 = A[(k0 + 3) * D + d];
#pragma unroll
        for (int u = 0; u < 8; ++u) {
            float4 xv = *(const float4*)&hs[rh * 8 + u][k0];
            acc2[u] += xv.x * w0 + xv.y * w1 + xv.z * w2 + xv.w * w3;
        }
    }
#pragma unroll
    for (int u = 0; u < 8; ++u)
        hA[((size_t)row0 + rh * 8 + u) * D + d] = acc2[u];
}

// ---- sparse S row + softmax stats: sval[i,s] = hA[i].h[j] + h[i].hA[j] ----
// block = row; 8 groups x 16 lanes (full 64B coalescing); each group
// processes TWO neighbors per iteration (16 gathers in flight).
__global__ __launch_bounds__(128) void k_Ssp(const float* __restrict__ h,
                                             const float* __restrict__ hA,
                                             const unsigned short* __restrict__ csr,
                                             const int* __restrict__ nnz,
                                             float* __restrict__ svals,
                                             float2* __restrict__ rowstat) {
    int row = blockIdx.x;
    int t = threadIdx.x;
    int base_row, N;
    size_t cbase;
    resolve_row(row, base_row, cbase, N);
    int n = nnz[row];
    int grp = t >> 4, u = t & 15;
    const float* hrow = h + (size_t)row * D + u * 8;
    const float* hArow = hA + (size_t)row * D + u * 8;
    float4 hi0 = *(const float4*)&hrow[0], hi1 = *(const float4*)&hrow[4];
    float4 ai0 = *(const float4*)&hArow[0], ai1 = *(const float4*)&hArow[4];
    __shared__ float sv[CAP2];
    for (int s0 = 0; s0 < n; s0 += 16) {
        int sa = s0 + grp;
        int sb = sa + 8;
        float pa = 0.f, pb = 0.f;
        if (sa < n) {
            int jrow = base_row + csr[cbase + sa];
            const float* hj = h + (size_t)jrow * D + u * 8;
            const float* aj = hA + (size_t)jrow * D + u * 8;
            float4 hj0 = *(const float4*)&hj[0], hj1 = *(const float4*)&hj[4];
            float4 aj0 = *(const float4*)&aj[0], aj1 = *(const float4*)&aj[4];
            pa = hi0.x * aj0.x + hi0.y * aj0.y + hi0.z * aj0.z + hi0.w * aj0.w +
                 hi1.x * aj1.x + hi1.y * aj1.y + hi1.z * aj1.z + hi1.w * aj1.w +
                 ai0.x * hj0.x + ai0.y * hj0.y + ai0.z * hj0.z + ai0.w * hj0.w +
                 ai1.x * hj1.x + ai1.y * hj1.y + ai1.z * hj1.z + ai1.w * hj1.w;
        }
        if (sb < n) {
            int jrow = base_row + csr[cbase + sb];
            const float* hj = h + (size_t)jrow * D + u * 8;
            const float* aj = hA + (size_t)jrow * D + u * 8;
            float4 hj0 = *(const float4*)&hj[0], hj1 = *(const float4*)&hj[4];
            float4 aj0 = *(const float4*)&aj[0], aj1 = *(const float4*)&aj[4];
            pb = hi0.x * aj0.x + hi0.y * aj0.y + hi0.z * aj0.z + hi0.w * aj0.w +
                 hi1.x * aj1.x + hi1.y * aj1.y + hi1.z * aj1.z + hi1.w * aj1.w +
                 ai0.x * hj0.x + ai0.y * hj0.y + ai0.z * hj0.z + ai0.w * hj0.w +
                 ai1.x * hj1.x + ai1.y * hj1.y + ai1.z * hj1.z + ai1.w * hj1.w;
        }
#pragma unroll
        for (int o = 8; o > 0; o >>= 1) {
            pa += __shfl_xor(pa, o);
            pb += __shfl_xor(pb, o);
        }
        if (u == 0) {
            if (sa < n) sv[sa] = pa;
            if (sb < n) sv[sb] = pb;
        }
    }
    __syncthreads();
    if (t < 64) {
        float m = -3.4e38f;
        for (int s = t; s < n; s += 64) m = fmaxf(m, sv[s]);
#pragma unroll
        for (int o = 32; o > 0; o >>= 1) m = fmaxf(m, __shfl_xor(m, o));
        float sum = 0.f;
        for (int s = t; s < n; s += 64) sum += expf(sv[s] - m);
#pragma unroll
        for (int o = 32; o > 0; o >>= 1) sum += __shfl_xor(sum, o);
        if (t == 0) rowstat[row] = make_float2(m, 1.f / sum);
    }
    for (int s = t; s < n; s += 128) svals[cbase + s] = sv[s];
}

// ------- h_prime via symmetry + gate (128 thr, 8-deep gather ILP) ----------
__global__ __launch_bounds__(128) void k_hpgate(const float* __restrict__ hbuf,
                                                float* __restrict__ g,
                                                const float* __restrict__ svals,
                                                const float2* __restrict__ rowstat,
                                                const unsigned short* __restrict__ csr,
                                                const int* __restrict__ nnz,
                                                const float* __restrict__ gW,
                                                const float* __restrict__ gb) {
    int row = blockIdx.x;
    int d = threadIdx.x;
    int base_row, N;
    size_t cbase;
    resolve_row(row, base_row, cbase, N);
    int n = nnz[row];
    __shared__ float avals[CAP2];
    __shared__ int aidx[CAP2];
    __shared__ float red[128];
    for (int s = d; s < n; s += 128) {
        int jrow = base_row + csr[cbase + s];
        float2 st = rowstat[jrow];
        avals[s] = expf(svals[cbase + s] - st.x) * st.y;
        aidx[s] = jrow;
    }
    __syncthreads();
    float a[8];
#pragma unroll
    for (int u = 0; u < 8; ++u) a[u] = 0.f;
    int s = 0;
    for (; s + 8 <= n; s += 8) {
#pragma unroll
        for (int u = 0; u < 8; ++u)
            a[u] += avals[s + u] * hbuf[(size_t)aidx[s + u] * D + d];
    }
    for (; s < n; ++s) a[0] += avals[s] * hbuf[(size_t)aidx[s] * D + d];
    float hv = fmaxf(((a[0] + a[1]) + (a[2] + a[3])) + ((a[4] + a[5]) + (a[6] + a[7])),
                     0.f);
    float xv = g[(size_t)row * D + d];
    red[d] = xv * gW[d] + hv * gW[D + d];
    __syncthreads();
    for (int o = 64; o > 0; o >>= 1) {
        if (d < o) red[d] += red[d + o];
        __syncthreads();
    }
    float c = 1.f / (1.f + expf(-(red[0] + gb[0])));
    g[(size_t)row * D + d] = c * xv + (1.f - c) * hv;
}

// ---------------- pair-MLP precompute: aA/aB = g @ W1{A,B} (+bias g1) ------
__global__ __launch_bounds__(256) void k_pairpre(const float* __restrict__ g,
                                                 const float* __restrict__ WA,
                                                 const float* __restrict__ WB,
                                                 const float* __restrict__ bA,
                                                 const float* __restrict__ bB,
                                                 float* __restrict__ aA,
                                                 float* __restrict__ aB) {
    int row0 = blockIdx.x * 16;
    int t = threadIdx.x;
    int d = t & 127, rh = t >> 7;
    int g2 = (row0 >= ROWS1);
    const float* WAp = g2 ? WA + D * D : WA;
    const float* WBp = g2 ? WB + D * D : WB;
    __shared__ float xs[16][D];
    {
        int r = t >> 4, c = (t & 15) * 8;
        *(float4*)&xs[r][c] = *(const float4*)&g[((size_t)row0 + r) * D + c];
        *(float4*)&xs[r][c + 4] = *(const float4*)&g[((size_t)row0 + r) * D + c + 4];
    }
    __syncthreads();
    float bvA = g2 ? 0.f : bA[d];
    float bvB = g2 ? 0.f : bB[d];
    float accA[8], accB[8];
#pragma unroll
    for (int u = 0; u < 8; ++u) { accA[u] = bvA; accB[u] = bvB; }
    for (int k0 = 0; k0 < D; k0 += 4) {
        float wa0 = WAp[(k0 + 0) * D + d], wa1 = WAp[(k0 + 1) * D + d];
        float wa2 = WAp[(k0 + 2) * D + d], wa3 = WAp[(k0 + 3) * D + d];
        float wb0 = WBp[(k0 + 0) * D + d], wb1 = WBp[(k0 + 1) * D + d];
        float wb2 = WBp[(k0 + 2) * D + d], wb3 = WBp[(k0 + 3) * D + d];
#pragma unroll
        for (int u = 0; u < 8; ++u) {
            float4 xv = *(const float4*)&xs[rh * 8 + u][k0];
            accA[u] += xv.x * wa0 + xv.y * wa1 + xv.z * wa2 + xv.w * wa3;
            accB[u] += xv.x * wb0 + xv.y * wb1 + xv.z * wb2 + xv.w * wb3;
        }
    }
#pragma unroll
    for (int u = 0; u < 8; ++u) {
        int r = rh * 8 + u;
        aA[((size_t)row0 + r) * D + d] = accA[u];
        aB[((size_t)row0 + r) * D + d] = accB[u];
    }
}

// --------- fused pair z-GEMM + energies + scaled atomic output ------------
__global__ __launch_bounds__(256) void k_pairz(
    const float* __restrict__ aA, const float* __restrict__ aB,
    const float* __restrict__ w2A, const float* __restrict__ w2B,
    const float* __restrict__ b2A, const float* __restrict__ b2B,
    const float* __restrict__ pos1, const float* __restrict__ pos2,
    const float* __restrict__ vr1, const float* __restrict__ vr2,
    const float* __restrict__ nm1, const float* __restrict__ nm2,
    const float* __restrict__ A_int, const float* __restrict__ rotor,
    const float* __restrict__ duff, const float* __restrict__ hbond,
    const float* __restrict__ hydro, const float* __restrict__ vdwc,
    const float* __restrict__ rotc, float* __restrict__ out) {
    int b = blockIdx.y;
    int itile = blockIdx.x >> 4, jtile = blockIdx.x & 15;
    int i0 = itile * 32, j0 = jtile * 32;
    int t = threadIdx.x;
    int tx = t & 15, ty = t >> 4;
    __shared__ float A1a[32][20], A1b[32][20], A2a[32][20], A2b[32][20];
    __shared__ float w2As[128], w2Bs[128];
    __shared__ float zAs[32][33], zBs[32][33];
    __shared__ float redc[8][4];
    if (t < 128) { w2As[t] = w2A[t]; w2Bs[t] = w2B[t]; }
    float zA[2][2] = {{0.f, 0.f}, {0.f, 0.f}};
    float zB[2][2] = {{0.f, 0.f}, {0.f, 0.f}};
    int half = t >> 7, idx = t & 127;
    int sr = idx >> 2, sc = (idx & 3) * 4;
    size_t grow = half ? (size_t)(ROWS1 + b * NN2 + j0 + sr)
                       : (size_t)(b * NN1 + i0 + sr);
    for (int hc = 0; hc < D; hc += 16) {
        __syncthreads();
        float4 va = *(const float4*)&aA[grow * D + hc + sc];
        float4 vb = *(const float4*)&aB[grow * D + hc + sc];
        if (half) { *(float4*)&A2a[sr][sc] = va; *(float4*)&A2b[sr][sc] = vb; }
        else      { *(float4*)&A1a[sr][sc] = va; *(float4*)&A1b[sr][sc] = vb; }
        __syncthreads();
#pragma unroll
        for (int hh = 0; hh < 16; hh += 4) {
            float4 wA = *(const float4*)&w2As[hc + hh];
            float4 wB = *(const float4*)&w2Bs[hc + hh];
            float4 xA0 = *(const float4*)&A1a[ty][hh];
            float4 xA1 = *(const float4*)&A1a[ty + 16][hh];
            float4 xB0 = *(const float4*)&A1b[ty][hh];
            float4 xB1 = *(const float4*)&A1b[ty + 16][hh];
            float4 yA0 = *(const float4*)&A2a[tx][hh];
            float4 yA1 = *(const float4*)&A2a[tx + 16][hh];
            float4 yB0 = *(const float4*)&A2b[tx][hh];
            float4 yB1 = *(const float4*)&A2b[tx + 16][hh];
#define RD4(xx, yy, ww) (fmaxf(xx.x + yy.x, 0.f) * ww.x + fmaxf(xx.y + yy.y, 0.f) * ww.y + \
                         fmaxf(xx.z + yy.z, 0.f) * ww.z + fmaxf(xx.w + yy.w, 0.f) * ww.w)
            zA[0][0] += RD4(xA0, yA0, wA); zA[0][1] += RD4(xA0, yA1, wA);
            zA[1][0] += RD4(xA1, yA0, wA); zA[1][1] += RD4(xA1, yA1, wA);
            zB[0][0] += RD4(xB0, yB0, wB); zB[0][1] += RD4(xB0, yB1, wB);
            zB[1][0] += RD4(xB1, yB0, wB); zB[1][1] += RD4(xB1, yB1, wB);
#undef RD4
        }
    }
#pragma unroll
    for (int u = 0; u < 2; ++u)
#pragma unroll
        for (int v = 0; v < 2; ++v) {
            zAs[ty + 16 * u][tx + 16 * v] = zA[u][v];
            zBs[ty + 16 * u][tx + 16 * v] = zB[u][v];
        }
    __syncthreads();
    int j2 = t & 31, ig = t >> 5;
    int jg = j0 + j2;
    size_t j_off = (size_t)b * NN2 + jg;
    float p2x = pos2[j_off * 3 + 0], p2y = pos2[j_off * 3 + 1], p2z = pos2[j_off * 3 + 2];
    float r2 = vr2[j_off], m2 = nm2[j_off];
    float zb2A = b2A[0], zb2B = b2B[0];
    float eV[4], e1[4], e2[4], eH[4];
#pragma unroll
    for (int ii = 0; ii < 4; ++ii) {
        int il = ig * 4 + ii;
        int iglob = i0 + il;
        size_t i_off = (size_t)b * NN1 + iglob;
        float zAv = zAs[il][j2] + zb2A;
        float zBv = zBs[il][j2] + zb2B;
        float dx = pos1[i_off * 3 + 0] - p2x;
        float dy = pos1[i_off * 3 + 1] - p2y;
        float dz = pos1[i_off * 3 + 2] - p2z;
        float dm = sqrtf(dx * dx + dy * dy + dz * dz + 1e-10f);
        if (dm < 0.5f) dm = 1e10f;
        float A_w = 1.f / (1.f + expf(-zAv));
        float B_w = tanhf(zBv) * 0.2f;
        float dm0 = vr1[i_off] + r2 + B_w;
        float dm0s = (dm0 < 1e-4f) ? 1.f : dm0;
        float rr = dm0s / dm;
        float rr2 = rr * rr;
        float rN = rr2 * rr2 * rr2;
        float evdw = fminf(rN * rN - 2.f * rN, 100.f);
        float mask = nm1[i_off] * m2;
        float Aamp = A_w * (0.0356f - 0.0178f) + 0.0178f;
        eV[ii] = Aamp * evdw * mask;
        float dmd = dm - dm0;
        size_t abase = (((size_t)b * 8) * NN1 + iglob) * NN2 + jg;
        float Ai1 = A_int[abase + (size_t)1 * NN1 * NN2];
        float Ai6 = A_int[abase + (size_t)6 * NN1 * NN2];
        float Ai7 = A_int[abase + (size_t)7 * NN1 * NN2];
        e1[ii] = fminf(fmaxf(dmd * Ai1 * (-1.f / 0.7f), 0.f), 1.f);
        e2[ii] = fminf(fmaxf(dmd * Ai7 * (-1.f / 0.7f), 0.f), 1.f);
        eH[ii] = fminf(fmaxf((1.5f - dmd) * Ai6, 0.f), 1.f);
    }
    float sV = (eV[0] + eV[1]) + (eV[2] + eV[3]);
    float s1 = (e1[0] + e1[1]) + (e1[2] + e1[3]);
    float s2 = (e2[0] + e2[1]) + (e2[2] + e2[3]);
    float sH = (eH[0] + eH[1]) + (eH[2] + eH[3]);
#pragma unroll
    for (int o = 16; o > 0; o >>= 1) {
        sV += __shfl_xor(sV, o);
        s1 += __shfl_xor(s1, o);
        s2 += __shfl_xor(s2, o);
        sH += __shfl_xor(sH, o);
    }
    if (j2 == 0) {
        redc[ig][0] = sV; redc[ig][1] = s1; redc[ig][2] = s2; redc[ig][3] = sH;
    }
    __syncthreads();
    if (t < 4) {
        float v = 0.f;
#pragma unroll
        for (int gg = 0; gg < 8; ++gg) v += redc[gg][t];
        float scl = 1.f / (1.f + rotc[0] * rotc[0] * rotor[b]);
        float coef;
        if (t == 0) coef = scl;
        else if (t == 3) coef = -hydro[0] * hydro[0] * scl;
        else coef = -hbond[0] * hbond[0] * scl;
        atomicAdd(&out[b * 5 + t], v * coef);
    }
    if (t == 4 && itile == 0 && jtile == 0) {
        float scl = 1.f / (1.f + rotc[0] * rotc[0] * rotor[b]);
        atomicAdd(&out[b * 5 + 4], duff[b] * vdwc[0] * vdwc[0] * scl);
    }
}

extern "C" void kernel_launch(void* const* d_in, const int* in_sizes, int n_in,
                              void* d_out, int out_size, void* d_ws, size_t ws_size,
                              hipStream_t stream) {
    const float* h1    = (const float*)d_in[0];
    const float* adj1  = (const float*)d_in[1];
    const float* h2    = (const float*)d_in[2];
    const float* adj2  = (const float*)d_in[3];
    const float* A_int = (const float*)d_in[4];
    const float* pos1  = (const float*)d_in[5];
    const float* pos2  = (const float*)d_in[6];
    const float* rotor = (const float*)d_in[7];
    const float* vr1   = (const float*)d_in[8];
    const float* vr2   = (const float*)d_in[9];
    const float* duff  = (const float*)d_in[10];
    const float* nm1   = (const float*)d_in[11];
    const float* nm2   = (const float*)d_in[12];
    const float* nodeW = (const float*)d_in[13];
    const float* gatW  = (const float*)d_in[14];
    const float* gatb  = (const float*)d_in[15];
    const float* gatA  = (const float*)d_in[16];
    const float* gateW = (const float*)d_in[17];
    const float* gateb = (const float*)d_in[18];
    const float* vA_W1 = (const float*)d_in[19];
    const float* vA_b1 = (const float*)d_in[20];
    const float* vA_W2 = (const float*)d_in[21];
    const float* vA_b2 = (const float*)d_in[22];
    const float* vB_W1 = (const float*)d_in[23];
    const float* vB_b1 = (const float*)d_in[24];
    const float* vB_W2 = (const float*)d_in[25];
    const float* vB_b2 = (const float*)d_in[26];
    const float* hbond = (const float*)d_in[27];
    const float* hydro = (const float*)d_in[28];
    const float* vdwc  = (const float*)d_in[29];
    const float* rotc  = (const float*)d_in[30];

    float* p = (float*)d_ws;
    float* g     = p; p += (size_t)ROWS * D;
    float* hbuf  = p; p += (size_t)ROWS * D;
    float* hAbuf = p; p += (size_t)ROWS * D;
    float* svals = p; p += CSR_ELEMS;
    float2* rowstat = (float2*)p; p += 2 * (size_t)ROWS;
    unsigned short* csr = (unsigned short*)p;
    int* nnz = (int*)(csr + CSR_ELEMS);
    float* aA = hbuf;   // aliases: hbuf/hAbuf dead after last k_hpgate
    float* aB = hAbuf;

    k_csrembed<<<ROWS, 128, 0, stream>>>(h1, h2, adj1, adj2, nodeW, g, csr, nnz,
                                         (float*)d_out);

    for (int l = 0; l < 3; ++l) {
        const float* W  = gatW  + (size_t)l * D * D;
        const float* bb = gatb  + (size_t)l * D;
        const float* A  = gatA  + (size_t)l * D * D;
        const float* gW = gateW + (size_t)l * 2 * D;
        const float* gb = gateb + l;
        k_h<<<ROWS / 16, 256, 0, stream>>>(g, W, bb, A, hbuf, hAbuf);
        k_Ssp<<<ROWS, 128, 0, stream>>>(hbuf, hAbuf, csr, nnz, svals, rowstat);
        k_hpgate<<<ROWS, 128, 0, stream>>>(hbuf, g, svals, rowstat, csr, nnz, gW, gb);
    }

    k_pairpre<<<ROWS / 16, 256, 0, stream>>>(g, vA_W1, vB_W1, vA_b1, vB_b1, aA, aB);
    k_pairz<<<dim3(64, NB), 256, 0, stream>>>(aA, aB, vA_W2, vB_W2, vA_b2, vB_b2,
                                              pos1, pos2, vr1, vr2, nm1, nm2, A_int,
                                              rotor, duff, hbond, hydro, vdwc, rotc,
                                              (float*)d_out);
}